// Round 23
// baseline (78.722 us; speedup 1.0000x reference)
//
#include <hip/hip_runtime.h>
#include <math.h>

typedef unsigned short ushort_t;
typedef unsigned int uint_t;
typedef __attribute__((ext_vector_type(8))) short bf16x8;
typedef __attribute__((ext_vector_type(16))) float f32x16;

// Problem constants (from reference)
constexpr int Bc   = 8;
constexpr int Nn   = 4500;
constexpr int Ec   = 72000;
constexpr int D    = 128;          // IN_DIM == OUT_DIM == 128
constexpr int T    = Bc * Nn;      // 36000 total nodes
constexpr int TE   = Bc * Ec;      // 576000 total edges
constexpr float EPS = 1e-5f;

constexpr int PAD = 32;            // ints per counter line (128B)
constexpr int RST = 64;            // edata slots per node (max deg ~45), 4B each

// k1 zones: GEMM (1 row-tile/block, 4 col-quarter waves) | zero cntp
constexpr int NB_GEMM   = T / 32;                     // 1125
constexpr int N_ZERO_I4 = (T * PAD) / 4;              // 288,000 int4 (exact)
constexpr int NB_ZERO   = N_ZERO_I4 / 256;            // 1125 (exact)
constexpr int NB_K1     = NB_GEMM + NB_ZERO;          // 2250

// Edge pass: XCD-pinned, 8 batches x 282 chunks
constexpr int NB_ECH  = (Ec + 255) / 256;      // 282
constexpr int NB_EDGE = 8 * NB_ECH;            // 2256

// Workspace layout (bytes), ~23 MB total.
constexpr size_t WS_CNTP  = 0;            // T*PAD u32: lo16=rank cnt, hi16=deg
constexpr size_t WS_EDATA = 4608000;      // T*RST u32 = 9,216,000
constexpr size_t WS_H     = 13824000;     // T*D bf16 = 9,216,000

__device__ __forceinline__ ushort_t f32_to_bf16_rne(float f) {
  uint_t u = __float_as_uint(f);
  uint_t r = (u + 0x7fffu + ((u >> 16) & 1u)) >> 16;
  return (ushort_t)r;
}
__device__ __forceinline__ float bf16_to_f32(ushort_t h) {
  return __uint_as_float(((uint_t)h) << 16);
}

// ---------------------------------------------------------------------------
// k1 (zoned): [0,1125) MFMA GEMM — block = ONE 32-row tile, 4 waves = 4
// col-quarters (32 cols each) sharing the A-tile via L1 (same r=lane&31
// mapping in all 4 waves -> 3 of 4 A-reads are L1 hits). Wave work halves
// vs the 2-n-tile shape, wave count doubles (4500) -> 2x TLP to hide the
// x-load->convert->MFMA chain. [1125,2250) zero cntp (256 int4/block exact).
// Inline-W hi-only; x split hi/lo in-register; 16 MFMAs/wave; bf16 h out.
// A/B frag: elem = lane&31, k = 8*(lane>>5)+j. C/D: col = lane&31,
// row = (j&3)+8*(j>>2)+4*(lane>>5).
// ---------------------------------------------------------------------------
__global__ __launch_bounds__(256) void gemm_zero_kernel(
    const float* __restrict__ x, const float* __restrict__ W,
    const float* __restrict__ bias, ushort_t* __restrict__ h,
    int4* __restrict__ zero4) {
  const int bid = blockIdx.x;
  if (bid < NB_GEMM) {
    const int ct   = threadIdx.x >> 6;     // col-quarter 0..3
    const int lane = threadIdx.x & 63;
    const int m0 = bid * 32;
    const int r  = lane & 31;
    const int kh = lane >> 5;

    const float* xrow = x + (size_t)(m0 + r) * D + kh * 8;

    f32x16 acc;
#pragma unroll
    for (int j = 0; j < 16; ++j) acc[j] = 0.f;

#pragma unroll
    for (int ks = 0; ks < 8; ++ks) {
      const float4 p0 = ((const float4*)(xrow + ks * 16))[0];
      const float4 p1 = ((const float4*)(xrow + ks * 16))[1];
      const float xa[8] = {p0.x, p0.y, p0.z, p0.w, p1.x, p1.y, p1.z, p1.w};
      bf16x8 ahi, alo;
#pragma unroll
      for (int j = 0; j < 8; ++j) {
        ushort_t hb = f32_to_bf16_rne(xa[j]);
        ahi[j] = (short)hb;
        alo[j] = (short)f32_to_bf16_rne(xa[j] - bf16_to_f32(hb));
      }
      const float* wrow = W + (size_t)(ct * 32 + r) * D + ks * 16 + kh * 8;
      const float4 w0 = ((const float4*)wrow)[0];
      const float4 w1 = ((const float4*)wrow)[1];
      bf16x8 bhi;
      bhi[0] = (short)f32_to_bf16_rne(w0.x);
      bhi[1] = (short)f32_to_bf16_rne(w0.y);
      bhi[2] = (short)f32_to_bf16_rne(w0.z);
      bhi[3] = (short)f32_to_bf16_rne(w0.w);
      bhi[4] = (short)f32_to_bf16_rne(w1.x);
      bhi[5] = (short)f32_to_bf16_rne(w1.y);
      bhi[6] = (short)f32_to_bf16_rne(w1.z);
      bhi[7] = (short)f32_to_bf16_rne(w1.w);
      acc = __builtin_amdgcn_mfma_f32_32x32x16_bf16(ahi, bhi, acc, 0, 0, 0);
      acc = __builtin_amdgcn_mfma_f32_32x32x16_bf16(alo, bhi, acc, 0, 0, 0);
    }

    const int col = ct * 32 + r;
    const float bv = bias[col];
#pragma unroll
    for (int j = 0; j < 16; ++j) {
      const int mrow = m0 + (j & 3) + 8 * (j >> 2) + 4 * kh;
      h[(size_t)mrow * D + col] = f32_to_bf16_rne(acc[j] + bv);
    }
  } else {
    int i = (bid - NB_GEMM) * 256 + threadIdx.x;   // < 288000 (exact fit)
    zero4[i] = make_int4(0, 0, 0, 0);              // cntp
  }
}

// ---------------------------------------------------------------------------
// Edge pass (XCD-pinned: bid&7 = batch): ONE packed fetch-add per edge:
//   lo16 += 1            -> rank (unique slot within the target's row)
//   hi16 += (ew != 0)    -> deg  (edge_mask is a 0/1 validity mask, so
//                                 deg = sum(ew) = count of valid edges)
// Max degree ~45 << 65536: no field carry. Placement:
//   edata[tgt*RST+rank] = bf16(ew)<<16 | src_local (4B).
// ---------------------------------------------------------------------------
__global__ __launch_bounds__(256) void edge_kernel(
    const int* __restrict__ ei, const float* __restrict__ em,
    uint_t* __restrict__ cntp, uint_t* __restrict__ edata) {
  const int b  = blockIdx.x & 7;
  const int el = (blockIdx.x >> 3) * 256 + threadIdx.x;
  if (el >= Ec) return;
  const int* eb = ei + b * 2 * Ec;
  int t0 = eb[Ec + el];
  if ((unsigned)t0 >= (unsigned)Nn) return;     // defensive
  int tg = t0 + b * Nn;
  float ew = em[b * Ec + el];
  uint_t pk_add = 1u + ((ew != 0.f) ? 0x10000u : 0u);
  uint_t ret = atomicAdd(&cntp[(size_t)tg * PAD], pk_add);
  uint_t rk  = ret & 0xFFFFu;
  if (rk >= (uint_t)RST) return;                // defensive (P ~ 0)
  int s0 = eb[el];
  uint_t sl = (uint_t)s0;
  if ((unsigned)s0 >= (unsigned)Nn) { sl = 0; ew = 0.f; }
  uint_t pk = ((uint_t)f32_to_bf16_rne(ew) << 16) | sl;
  edata[(size_t)tg * RST + rk] = pk;
}

// ---------------------------------------------------------------------------
// Fused gather + residual + LayerNorm + ReLU + mask (packed edata, bf16 h).
// dinv computed INLINE: dinv[i] = rsqrt((cntp[i*PAD]>>16) + 1).
// XCD-pinned: bid%8 = batch (h slice 1.15MB + cntp slice 576KB -> per-XCD L2).
// ---------------------------------------------------------------------------
__global__ __launch_bounds__(256) void gather_ln_kernel(
    const ushort_t* __restrict__ h, const uint_t* __restrict__ cntp,
    const uint_t* __restrict__ edata, const float* __restrict__ gamma,
    const float* __restrict__ beta, const float* __restrict__ mask,
    float* __restrict__ out) {
  const int bid  = blockIdx.x;                  // 9000 = 8 * 1125
  const int b    = bid & 7;
  const int wid  = threadIdx.x >> 6;
  const int node = b * Nn + (bid >> 3) * 4 + wid;
  const int bOff = b * Nn;
  const int lane = threadIdx.x & 63;
  const int f4   = lane & 31;
  const int half = lane >> 5;

  const ushort4* h4 = (const ushort4*)h;
  const uint_t u = cntp[(size_t)node * PAD];
  int cnt = (int)(u & 0xFFFFu);
  cnt = (cnt > RST) ? RST : cnt;
  const float dt = rsqrtf((float)(u >> 16) + 1.0f);
  const uint_t* row = edata + (size_t)node * RST;

  ushort4 hq = h4[(size_t)node * 32 + f4];
  float4 hv = make_float4(bf16_to_f32(hq.x), bf16_to_f32(hq.y),
                          bf16_to_f32(hq.z), bf16_to_f32(hq.w));

  float4 accE = make_float4(0.f, 0.f, 0.f, 0.f);
  int i = half;
  for (; i + 6 < cnt; i += 8) {
    uint_t p0 = row[i];
    uint_t p1 = row[i + 2];
    uint_t p2 = row[i + 4];
    uint_t p3 = row[i + 6];
    int sg0 = bOff + (p0 & 0xFFFFu);
    int sg1 = bOff + (p1 & 0xFFFFu);
    int sg2 = bOff + (p2 & 0xFFFFu);
    int sg3 = bOff + (p3 & 0xFFFFu);
    float c0 = rsqrtf((float)(cntp[(size_t)sg0 * PAD] >> 16) + 1.0f) *
               bf16_to_f32((ushort_t)(p0 >> 16));
    float c1 = rsqrtf((float)(cntp[(size_t)sg1 * PAD] >> 16) + 1.0f) *
               bf16_to_f32((ushort_t)(p1 >> 16));
    float c2 = rsqrtf((float)(cntp[(size_t)sg2 * PAD] >> 16) + 1.0f) *
               bf16_to_f32((ushort_t)(p2 >> 16));
    float c3 = rsqrtf((float)(cntp[(size_t)sg3 * PAD] >> 16) + 1.0f) *
               bf16_to_f32((ushort_t)(p3 >> 16));
    ushort4 q0 = h4[(size_t)sg0 * 32 + f4];
    ushort4 q1 = h4[(size_t)sg1 * 32 + f4];
    ushort4 q2 = h4[(size_t)sg2 * 32 + f4];
    ushort4 q3 = h4[(size_t)sg3 * 32 + f4];
    accE.x += bf16_to_f32(q0.x) * c0 + bf16_to_f32(q1.x) * c1 +
              bf16_to_f32(q2.x) * c2 + bf16_to_f32(q3.x) * c3;
    accE.y += bf16_to_f32(q0.y) * c0 + bf16_to_f32(q1.y) * c1 +
              bf16_to_f32(q2.y) * c2 + bf16_to_f32(q3.y) * c3;
    accE.z += bf16_to_f32(q0.z) * c0 + bf16_to_f32(q1.z) * c1 +
              bf16_to_f32(q2.z) * c2 + bf16_to_f32(q3.z) * c3;
    accE.w += bf16_to_f32(q0.w) * c0 + bf16_to_f32(q1.w) * c1 +
              bf16_to_f32(q2.w) * c2 + bf16_to_f32(q3.w) * c3;
  }
  for (; i < cnt; i += 2) {
    uint_t p0 = row[i];
    int sg0 = bOff + (p0 & 0xFFFFu);
    float c0 = rsqrtf((float)(cntp[(size_t)sg0 * PAD] >> 16) + 1.0f) *
               bf16_to_f32((ushort_t)(p0 >> 16));
    ushort4 q0 = h4[(size_t)sg0 * 32 + f4];
    accE.x += bf16_to_f32(q0.x) * c0;
    accE.y += bf16_to_f32(q0.y) * c0;
    accE.z += bf16_to_f32(q0.z) * c0;
    accE.w += bf16_to_f32(q0.w) * c0;
  }

  accE.x += __shfl_xor(accE.x, 32);
  accE.y += __shfl_xor(accE.y, 32);
  accE.z += __shfl_xor(accE.z, 32);
  accE.w += __shfl_xor(accE.w, 32);

  float4 acc;
  acc.x = hv.x * (1.f + dt) + dt * accE.x;
  acc.y = hv.y * (1.f + dt) + dt * accE.y;
  acc.z = hv.z * (1.f + dt) + dt * accE.z;
  acc.w = hv.w * (1.f + dt) + dt * accE.w;

  float su = acc.x + acc.y + acc.z + acc.w;
  float ss = acc.x * acc.x + acc.y * acc.y + acc.z * acc.z + acc.w * acc.w;
#pragma unroll
  for (int o = 16; o > 0; o >>= 1) {
    su += __shfl_xor(su, o);
    ss += __shfl_xor(ss, o);
  }
  float mu  = su * (1.0f / 128.0f);
  float var = ss * (1.0f / 128.0f) - mu * mu;
  float rs  = 1.0f / sqrtf(var + EPS);
  float m   = mask[node];

  float4 g  = ((const float4*)gamma)[f4];
  float4 bb = ((const float4*)beta)[f4];
  float4 rv;
  rv.x = fmaxf((acc.x - mu) * rs * g.x + bb.x, 0.f) * m;
  rv.y = fmaxf((acc.y - mu) * rs * g.y + bb.y, 0.f) * m;
  rv.z = fmaxf((acc.z - mu) * rs * g.z + bb.z, 0.f) * m;
  rv.w = fmaxf((acc.w - mu) * rs * g.w + bb.w, 0.f) * m;
  if (half == 0) ((float4*)out)[(size_t)node * 32 + f4] = rv;
}

// ---------------------------------------------------------------------------
extern "C" void kernel_launch(void* const* d_in, const int* in_sizes, int n_in,
                              void* d_out, int out_size, void* d_ws, size_t ws_size,
                              hipStream_t stream) {
  const float* x     = (const float*)d_in[0];
  const int*   ei    = (const int*)d_in[1];
  const float* nmask = (const float*)d_in[2];
  const float* emask = (const float*)d_in[3];
  const float* W     = (const float*)d_in[4];
  const float* bias  = (const float*)d_in[5];
  const float* gamma = (const float*)d_in[6];
  const float* beta  = (const float*)d_in[7];
  float* out = (float*)d_out;

  char*     ws    = (char*)d_ws;
  uint_t*   cntp  = (uint_t*)  (ws + WS_CNTP);
  uint_t*   edata = (uint_t*)  (ws + WS_EDATA);
  ushort_t* h     = (ushort_t*)(ws + WS_H);

  // k1: GEMM (1125 row-tile blocks, 4 col-quarter waves) + zero cntp.
  gemm_zero_kernel<<<NB_K1, 256, 0, stream>>>(x, W, bias, h, (int4*)cntp);
  // k2: edge pass (single packed rank+deg atomic, packed CSR placement).
  edge_kernel<<<NB_EDGE, 256, 0, stream>>>(ei, emask, cntp, edata);
  // k3: gather + LN (dinv inline from cntp's deg field).
  gather_ln_kernel<<<T / 4, 256, 0, stream>>>(h, cntp, edata,
                                              gamma, beta, nmask, out);
}

// Round 24
// 77.469 us; speedup vs baseline: 1.0162x; 1.0162x over previous
//
#include <hip/hip_runtime.h>
#include <math.h>

typedef unsigned short ushort_t;
typedef unsigned int uint_t;
typedef __attribute__((ext_vector_type(8))) short bf16x8;
typedef __attribute__((ext_vector_type(16))) float f32x16;

// Problem constants (from reference)
constexpr int Bc   = 8;
constexpr int Nn   = 4500;
constexpr int Ec   = 72000;
constexpr int D    = 128;          // IN_DIM == OUT_DIM == 128
constexpr int T    = Bc * Nn;      // 36000 total nodes
constexpr int TE   = Bc * Ec;      // 576000 total edges
constexpr float EPS = 1e-5f;

constexpr int PAD = 32;            // ints per counter line (128B)
constexpr int RST = 64;            // edata slots per node (max deg ~45), 4B each

// k1 zones: GEMM | zero cntp (4.6MB, exact fit)
constexpr int NB_GEMM   = ((T / 32) * 2 + 3) / 4;     // 563
constexpr int N_ZERO_I4 = (T * PAD) / 4;              // 288,000 int4 (exact)
constexpr int NB_ZERO   = N_ZERO_I4 / 256;            // 1125 (exact)
constexpr int NB_K1     = NB_GEMM + NB_ZERO;          // 1688

// Edge pass: XCD-pinned, 8 batches x 282 chunks
constexpr int NB_ECH  = (Ec + 255) / 256;      // 282
constexpr int NB_EDGE = 8 * NB_ECH;            // 2256

// Workspace layout (bytes), ~23 MB total.
constexpr size_t WS_CNTP  = 0;            // T*PAD u32: lo16=rank cnt, hi16=deg
constexpr size_t WS_EDATA = 4608000;      // T*RST u32 = 9,216,000
constexpr size_t WS_H     = 13824000;     // T*D bf16 = 9,216,000

__device__ __forceinline__ ushort_t f32_to_bf16_rne(float f) {
  uint_t u = __float_as_uint(f);
  uint_t r = (u + 0x7fffu + ((u >> 16) & 1u)) >> 16;
  return (ushort_t)r;
}
__device__ __forceinline__ float bf16_to_f32(ushort_t h) {
  return __uint_as_float(((uint_t)h) << 16);
}

// ---------------------------------------------------------------------------
// k1 (zoned): [0,563) MFMA GEMM (inline-W hi-only, x split hi/lo in-register,
// bf16 h out); [563,1688) zero cntp (int4, exact fit). GEMM precedes the
// edge pass, so the zero zone legally replaces the old prep kernel.
// Wave = 32 rows x 64 cols; 32 MFMAs/wave.
// A/B frag: elem = lane&31, k = 8*(lane>>5)+j. C/D: col = lane&31,
// row = (j&3)+8*(j>>2)+4*(lane>>5).
// ---------------------------------------------------------------------------
__global__ __launch_bounds__(256) void gemm_zero_kernel(
    const float* __restrict__ x, const float* __restrict__ W,
    const float* __restrict__ bias, ushort_t* __restrict__ h,
    int4* __restrict__ zero4) {
  const int bid = blockIdx.x;
  if (bid < NB_GEMM) {
    const int g = bid * 4 + (threadIdx.x >> 6);
    if (g >= (T / 32) * 2) return;
    const int lane = threadIdx.x & 63;
    const int mt = g >> 1;          // row-tile
    const int nh = g & 1;           // col-half (64 cols)
    const int m0 = mt * 32;
    const int r  = lane & 31;
    const int kh = lane >> 5;

    const float* xrow = x + (size_t)(m0 + r) * D + kh * 8;

    f32x16 acc[2];
#pragma unroll
    for (int n = 0; n < 2; ++n)
#pragma unroll
      for (int j = 0; j < 16; ++j) acc[n][j] = 0.f;

#pragma unroll
    for (int ks = 0; ks < 8; ++ks) {
      const float4 p0 = ((const float4*)(xrow + ks * 16))[0];
      const float4 p1 = ((const float4*)(xrow + ks * 16))[1];
      const float xa[8] = {p0.x, p0.y, p0.z, p0.w, p1.x, p1.y, p1.z, p1.w};
      bf16x8 ahi, alo;
#pragma unroll
      for (int j = 0; j < 8; ++j) {
        ushort_t hb = f32_to_bf16_rne(xa[j]);
        ahi[j] = (short)hb;
        alo[j] = (short)f32_to_bf16_rne(xa[j] - bf16_to_f32(hb));
      }
#pragma unroll
      for (int n = 0; n < 2; ++n) {
        const float* wrow = W + (size_t)((nh * 2 + n) * 32 + r) * D
                              + ks * 16 + kh * 8;
        const float4 w0 = ((const float4*)wrow)[0];
        const float4 w1 = ((const float4*)wrow)[1];
        bf16x8 bhi;
        bhi[0] = (short)f32_to_bf16_rne(w0.x);
        bhi[1] = (short)f32_to_bf16_rne(w0.y);
        bhi[2] = (short)f32_to_bf16_rne(w0.z);
        bhi[3] = (short)f32_to_bf16_rne(w0.w);
        bhi[4] = (short)f32_to_bf16_rne(w1.x);
        bhi[5] = (short)f32_to_bf16_rne(w1.y);
        bhi[6] = (short)f32_to_bf16_rne(w1.z);
        bhi[7] = (short)f32_to_bf16_rne(w1.w);
        acc[n] = __builtin_amdgcn_mfma_f32_32x32x16_bf16(ahi, bhi, acc[n], 0, 0, 0);
        acc[n] = __builtin_amdgcn_mfma_f32_32x32x16_bf16(alo, bhi, acc[n], 0, 0, 0);
      }
    }

#pragma unroll
    for (int n = 0; n < 2; ++n) {
      const int col = (nh * 2 + n) * 32 + r;
      const float bv = bias[col];
#pragma unroll
      for (int j = 0; j < 16; ++j) {
        const int mrow = m0 + (j & 3) + 8 * (j >> 2) + 4 * kh;
        h[(size_t)mrow * D + col] = f32_to_bf16_rne(acc[n][j] + bv);
      }
    }
  } else {
    int i = (bid - NB_GEMM) * 256 + threadIdx.x;   // < 288000 (exact fit)
    zero4[i] = make_int4(0, 0, 0, 0);              // cntp
  }
}

// ---------------------------------------------------------------------------
// Edge pass (XCD-pinned: bid&7 = batch): ONE packed fetch-add per edge:
//   lo16 += 1            -> rank (unique slot within the target's row)
//   hi16 += (ew != 0)    -> deg  (edge_mask is a 0/1 validity mask, so
//                                 deg = sum(ew) = count of valid edges)
// Max degree ~45 << 65536: no field carry. Placement:
//   edata[tgt*RST+rank] = bf16(ew)<<16 | src_local (4B).
// R11/R19 lesson: a SECOND per-edge atomic doubles edge cost — this packs
// deg into the atomic we already pay for.
// ---------------------------------------------------------------------------
__global__ __launch_bounds__(256) void edge_kernel(
    const int* __restrict__ ei, const float* __restrict__ em,
    uint_t* __restrict__ cntp, uint_t* __restrict__ edata) {
  const int b  = blockIdx.x & 7;
  const int el = (blockIdx.x >> 3) * 256 + threadIdx.x;
  if (el >= Ec) return;
  const int* eb = ei + b * 2 * Ec;
  int t0 = eb[Ec + el];
  if ((unsigned)t0 >= (unsigned)Nn) return;     // defensive
  int tg = t0 + b * Nn;
  float ew = em[b * Ec + el];
  uint_t pk_add = 1u + ((ew != 0.f) ? 0x10000u : 0u);
  uint_t ret = atomicAdd(&cntp[(size_t)tg * PAD], pk_add);
  uint_t rk  = ret & 0xFFFFu;
  if (rk >= (uint_t)RST) return;                // defensive (P ~ 0)
  int s0 = eb[el];
  uint_t sl = (uint_t)s0;
  if ((unsigned)s0 >= (unsigned)Nn) { sl = 0; ew = 0.f; }
  uint_t pk = ((uint_t)f32_to_bf16_rne(ew) << 16) | sl;
  edata[(size_t)tg * RST + rk] = pk;
}

// ---------------------------------------------------------------------------
// Fused gather + residual + LayerNorm + ReLU + mask (packed edata, bf16 h).
// dinv computed INLINE: dinv[i] = rsqrt((cntp[i*PAD]>>16) + 1).
// XCD-pinned: bid%8 = batch (h slice 1.15MB + cntp slice 576KB -> per-XCD L2).
// ---------------------------------------------------------------------------
__global__ __launch_bounds__(256) void gather_ln_kernel(
    const ushort_t* __restrict__ h, const uint_t* __restrict__ cntp,
    const uint_t* __restrict__ edata, const float* __restrict__ gamma,
    const float* __restrict__ beta, const float* __restrict__ mask,
    float* __restrict__ out) {
  const int bid  = blockIdx.x;                  // 9000 = 8 * 1125
  const int b    = bid & 7;
  const int wid  = threadIdx.x >> 6;
  const int node = b * Nn + (bid >> 3) * 4 + wid;
  const int bOff = b * Nn;
  const int lane = threadIdx.x & 63;
  const int f4   = lane & 31;
  const int half = lane >> 5;

  const ushort4* h4 = (const ushort4*)h;
  const uint_t u = cntp[(size_t)node * PAD];
  int cnt = (int)(u & 0xFFFFu);
  cnt = (cnt > RST) ? RST : cnt;
  const float dt = rsqrtf((float)(u >> 16) + 1.0f);
  const uint_t* row = edata + (size_t)node * RST;

  ushort4 hq = h4[(size_t)node * 32 + f4];
  float4 hv = make_float4(bf16_to_f32(hq.x), bf16_to_f32(hq.y),
                          bf16_to_f32(hq.z), bf16_to_f32(hq.w));

  float4 accE = make_float4(0.f, 0.f, 0.f, 0.f);
  int i = half;
  for (; i + 6 < cnt; i += 8) {
    uint_t p0 = row[i];
    uint_t p1 = row[i + 2];
    uint_t p2 = row[i + 4];
    uint_t p3 = row[i + 6];
    int sg0 = bOff + (p0 & 0xFFFFu);
    int sg1 = bOff + (p1 & 0xFFFFu);
    int sg2 = bOff + (p2 & 0xFFFFu);
    int sg3 = bOff + (p3 & 0xFFFFu);
    float c0 = rsqrtf((float)(cntp[(size_t)sg0 * PAD] >> 16) + 1.0f) *
               bf16_to_f32((ushort_t)(p0 >> 16));
    float c1 = rsqrtf((float)(cntp[(size_t)sg1 * PAD] >> 16) + 1.0f) *
               bf16_to_f32((ushort_t)(p1 >> 16));
    float c2 = rsqrtf((float)(cntp[(size_t)sg2 * PAD] >> 16) + 1.0f) *
               bf16_to_f32((ushort_t)(p2 >> 16));
    float c3 = rsqrtf((float)(cntp[(size_t)sg3 * PAD] >> 16) + 1.0f) *
               bf16_to_f32((ushort_t)(p3 >> 16));
    ushort4 q0 = h4[(size_t)sg0 * 32 + f4];
    ushort4 q1 = h4[(size_t)sg1 * 32 + f4];
    ushort4 q2 = h4[(size_t)sg2 * 32 + f4];
    ushort4 q3 = h4[(size_t)sg3 * 32 + f4];
    accE.x += bf16_to_f32(q0.x) * c0 + bf16_to_f32(q1.x) * c1 +
              bf16_to_f32(q2.x) * c2 + bf16_to_f32(q3.x) * c3;
    accE.y += bf16_to_f32(q0.y) * c0 + bf16_to_f32(q1.y) * c1 +
              bf16_to_f32(q2.y) * c2 + bf16_to_f32(q3.y) * c3;
    accE.z += bf16_to_f32(q0.z) * c0 + bf16_to_f32(q1.z) * c1 +
              bf16_to_f32(q2.z) * c2 + bf16_to_f32(q3.z) * c3;
    accE.w += bf16_to_f32(q0.w) * c0 + bf16_to_f32(q1.w) * c1 +
              bf16_to_f32(q2.w) * c2 + bf16_to_f32(q3.w) * c3;
  }
  for (; i < cnt; i += 2) {
    uint_t p0 = row[i];
    int sg0 = bOff + (p0 & 0xFFFFu);
    float c0 = rsqrtf((float)(cntp[(size_t)sg0 * PAD] >> 16) + 1.0f) *
               bf16_to_f32((ushort_t)(p0 >> 16));
    ushort4 q0 = h4[(size_t)sg0 * 32 + f4];
    accE.x += bf16_to_f32(q0.x) * c0;
    accE.y += bf16_to_f32(q0.y) * c0;
    accE.z += bf16_to_f32(q0.z) * c0;
    accE.w += bf16_to_f32(q0.w) * c0;
  }

  accE.x += __shfl_xor(accE.x, 32);
  accE.y += __shfl_xor(accE.y, 32);
  accE.z += __shfl_xor(accE.z, 32);
  accE.w += __shfl_xor(accE.w, 32);

  float4 acc;
  acc.x = hv.x * (1.f + dt) + dt * accE.x;
  acc.y = hv.y * (1.f + dt) + dt * accE.y;
  acc.z = hv.z * (1.f + dt) + dt * accE.z;
  acc.w = hv.w * (1.f + dt) + dt * accE.w;

  float su = acc.x + acc.y + acc.z + acc.w;
  float ss = acc.x * acc.x + acc.y * acc.y + acc.z * acc.z + acc.w * acc.w;
#pragma unroll
  for (int o = 16; o > 0; o >>= 1) {
    su += __shfl_xor(su, o);
    ss += __shfl_xor(ss, o);
  }
  float mu  = su * (1.0f / 128.0f);
  float var = ss * (1.0f / 128.0f) - mu * mu;
  float rs  = 1.0f / sqrtf(var + EPS);
  float m   = mask[node];

  float4 g  = ((const float4*)gamma)[f4];
  float4 bb = ((const float4*)beta)[f4];
  float4 rv;
  rv.x = fmaxf((acc.x - mu) * rs * g.x + bb.x, 0.f) * m;
  rv.y = fmaxf((acc.y - mu) * rs * g.y + bb.y, 0.f) * m;
  rv.z = fmaxf((acc.z - mu) * rs * g.z + bb.z, 0.f) * m;
  rv.w = fmaxf((acc.w - mu) * rs * g.w + bb.w, 0.f) * m;
  if (half == 0) ((float4*)out)[(size_t)node * 32 + f4] = rv;
}

// ---------------------------------------------------------------------------
extern "C" void kernel_launch(void* const* d_in, const int* in_sizes, int n_in,
                              void* d_out, int out_size, void* d_ws, size_t ws_size,
                              hipStream_t stream) {
  const float* x     = (const float*)d_in[0];
  const int*   ei    = (const int*)d_in[1];
  const float* nmask = (const float*)d_in[2];
  const float* emask = (const float*)d_in[3];
  const float* W     = (const float*)d_in[4];
  const float* bias  = (const float*)d_in[5];
  const float* gamma = (const float*)d_in[6];
  const float* beta  = (const float*)d_in[7];
  float* out = (float*)d_out;

  char*     ws    = (char*)d_ws;
  uint_t*   cntp  = (uint_t*)  (ws + WS_CNTP);
  uint_t*   edata = (uint_t*)  (ws + WS_EDATA);
  ushort_t* h     = (ushort_t*)(ws + WS_H);

  // k1: GEMM + zero cntp (independent zones; GEMM precedes edge pass).
  gemm_zero_kernel<<<NB_K1, 256, 0, stream>>>(x, W, bias, h, (int4*)cntp);
  // k2: edge pass (single packed rank+deg atomic, packed CSR placement).
  edge_kernel<<<NB_EDGE, 256, 0, stream>>>(ei, emask, cntp, edata);
  // k3: gather + LN (dinv inline from cntp's deg field).
  gather_ln_kernel<<<T / 4, 256, 0, stream>>>(h, cntp, edata,
                                              gamma, beta, nmask, out);
}